// Round 1
// baseline (4737.207 us; speedup 1.0000x reference)
//
#include <hip/hip_runtime.h>
#include <stdint.h>

typedef unsigned short ushort_t;
typedef unsigned int u32;
typedef unsigned long long u64;

#define NC_ 16384
#define NS_ 16384
#define DIM 2688
#define D4 (DIM / 4)       // 672 float4 per row
#define KSTEPS (DIM / 32)  // 84

typedef __attribute__((ext_vector_type(8))) short short8;
typedef __attribute__((ext_vector_type(4))) float f32x4;

// ---------- helpers ----------

__device__ inline ushort_t f2bf(float x) {
  u32 u = __float_as_uint(x);
  u32 r = u + 0x7FFFu + ((u >> 16) & 1u);  // RNE
  return (ushort_t)(r >> 16);
}
__device__ inline float bf2f(ushort_t b) { return __uint_as_float(((u32)b) << 16); }

// monotone float -> uint mapping (finite inputs)
__device__ inline u32 fkey(float f) {
  u32 u = __float_as_uint(f);
  return (u & 0x80000000u) ? ~u : (u | 0x80000000u);
}

__device__ inline void async16(const void* g, void* l) {
  __builtin_amdgcn_global_load_lds(
      (const __attribute__((address_space(1))) u32*)g,
      (__attribute__((address_space(3))) u32*)l, 16, 0, 0);
}

// ---------- kernel 1: split content fp32 -> bf16 hi/lo ----------

__global__ __launch_bounds__(256) void content_split_kernel(
    const float* __restrict__ fc, ushort_t* __restrict__ c_hi, ushort_t* __restrict__ c_lo) {
  size_t i = (size_t)blockIdx.x * 256 + threadIdx.x;
  if (i >= (size_t)NC_ * DIM / 4) return;
  float4 v = ((const float4*)fc)[i];
  ushort4 h, l;
  h.x = f2bf(v.x); l.x = f2bf(v.x - bf2f(h.x));
  h.y = f2bf(v.y); l.y = f2bf(v.y - bf2f(h.y));
  h.z = f2bf(v.z); l.z = f2bf(v.z - bf2f(h.z));
  h.w = f2bf(v.w); l.w = f2bf(v.w - bf2f(h.w));
  ((ushort4*)c_hi)[i] = h;
  ((ushort4*)c_lo)[i] = l;
}

// ---------- kernel 2: style row-normalize + split ----------

__global__ __launch_bounds__(256) void style_split_kernel(
    const float* __restrict__ fs, ushort_t* __restrict__ s_hi, ushort_t* __restrict__ s_lo) {
  const int s = blockIdx.x, t = threadIdx.x;
  const float4* row = (const float4*)(fs + (size_t)s * DIM);
  float ss = 0.f;
  for (int i = t; i < D4; i += 256) {
    float4 v = row[i];
    ss += v.x * v.x + v.y * v.y + v.z * v.z + v.w * v.w;
  }
#pragma unroll
  for (int off = 32; off >= 1; off >>= 1) ss += __shfl_xor(ss, off, 64);
  __shared__ float wsum[4];
  if ((t & 63) == 0) wsum[t >> 6] = ss;
  __syncthreads();
  float scale = rsqrtf(wsum[0] + wsum[1] + wsum[2] + wsum[3] + 1e-8f);
  ushort4* h4 = (ushort4*)(s_hi + (size_t)s * DIM);
  ushort4* l4 = (ushort4*)(s_lo + (size_t)s * DIM);
  for (int i = t; i < D4; i += 256) {
    float4 v = row[i];
    float x = v.x * scale, y = v.y * scale, z = v.z * scale, w = v.w * scale;
    ushort4 h, l;
    h.x = f2bf(x); l.x = f2bf(x - bf2f(h.x));
    h.y = f2bf(y); l.y = f2bf(y - bf2f(h.y));
    h.z = f2bf(z); l.z = f2bf(z - bf2f(h.z));
    h.w = f2bf(w); l.w = f2bf(w - bf2f(h.w));
    h4[i] = h;
    l4[i] = l;
  }
}

// ---------- kernel 3: 128x128-tile sim GEMM (bf16x3) + per-tile row argmax ----------
// partial[m * 128 + sb] = packed (fkey(max sim) << 32) | (0xFFFFFFFF - argmax_col)

__global__ __launch_bounds__(256) void sim_argmax_kernel(
    const ushort_t* __restrict__ c_hi, const ushort_t* __restrict__ c_lo,
    const ushort_t* __restrict__ s_hi, const ushort_t* __restrict__ s_lo,
    u64* __restrict__ partial) {
  __shared__ __align__(16) ushort_t lds[4 * 128 * 32];  // 32 KiB
  __shared__ u64 red[256];

  ushort_t* la_hi = lds;
  ushort_t* la_lo = lds + 4096;
  ushort_t* lb_hi = lds + 8192;
  ushort_t* lb_lo = lds + 12288;

  const int t = threadIdx.x;
  const int bid = blockIdx.x;
  // 16x16 block supertiles for LLC/L2 locality
  const int grp = bid >> 8;
  const int wi = bid & 255;
  const int cb = (grp & 7) * 16 + (wi & 15);
  const int sb = (grp >> 3) * 16 + (wi >> 4);

  const ushort_t* gah = c_hi + (size_t)cb * 128 * DIM;
  const ushort_t* gal = c_lo + (size_t)cb * 128 * DIM;
  const ushort_t* gbh = s_hi + (size_t)sb * 128 * DIM;
  const ushort_t* gbl = s_lo + (size_t)sb * 128 * DIM;

  const int lane = t & 63;
  const int wave = t >> 6;
  const int wy = wave >> 1, wx = wave & 1;  // 2x2 wave grid, 64x64 per wave
  const int lm = lane & 15, q = lane >> 4;

  f32x4 acc[4][4];
#pragma unroll
  for (int i = 0; i < 4; i++)
#pragma unroll
    for (int j = 0; j < 4; j++) acc[i][j] = (f32x4){0.f, 0.f, 0.f, 0.f};

  const int tw = t & 192;  // wave base within 256 threads

  for (int ks = 0; ks < KSTEPS; ++ks) {
    const int kel = ks * 32;
#pragma unroll
    for (int j = 0; j < 2; ++j) {
      int e = j * 256 + t;          // 16B-chunk index: row = e>>2, chunk = e&3
      int row = e >> 2, c4 = e & 3;
      size_t goff = (size_t)row * DIM + kel + c4 * 8;  // in ushort elements
      int loff = (j * 256 + tw) * 8;                   // wave-uniform LDS segment base
      async16(gah + goff, la_hi + loff);
      async16(gal + goff, la_lo + loff);
      async16(gbh + goff, lb_hi + loff);
      async16(gbl + goff, lb_lo + loff);
    }
    __syncthreads();

    short8 ah[4], al[4], bh[4], bl[4];
#pragma unroll
    for (int mi = 0; mi < 4; ++mi) {
      int r = (wy * 64 + mi * 16 + lm) * 32 + q * 8;
      ah[mi] = *(const short8*)(la_hi + r);
      al[mi] = *(const short8*)(la_lo + r);
    }
#pragma unroll
    for (int ni = 0; ni < 4; ++ni) {
      int r = (wx * 64 + ni * 16 + lm) * 32 + q * 8;
      bh[ni] = *(const short8*)(lb_hi + r);
      bl[ni] = *(const short8*)(lb_lo + r);
    }
#pragma unroll
    for (int mi = 0; mi < 4; ++mi)
#pragma unroll
      for (int ni = 0; ni < 4; ++ni) {
        acc[mi][ni] = __builtin_amdgcn_mfma_f32_16x16x32_bf16(ah[mi], bh[ni], acc[mi][ni], 0, 0, 0);
        acc[mi][ni] = __builtin_amdgcn_mfma_f32_16x16x32_bf16(ah[mi], bl[ni], acc[mi][ni], 0, 0, 0);
        acc[mi][ni] = __builtin_amdgcn_mfma_f32_16x16x32_bf16(al[mi], bh[ni], acc[mi][ni], 0, 0, 0);
      }
    __syncthreads();
  }

  // per-row argmax over this block's 128 style columns
  // C layout (16x16x32): col = lane&15, row = (lane>>4)*4 + reg
#pragma unroll
  for (int mi = 0; mi < 4; ++mi) {
#pragma unroll
    for (int r = 0; r < 4; ++r) {
      float bv = acc[mi][0][r];
      int bn = 0;
#pragma unroll
      for (int ni = 1; ni < 4; ++ni) {
        float v = acc[mi][ni][r];
        if (v > bv) { bv = v; bn = ni; }
      }
      u32 colg = (u32)(sb * 128 + wx * 64 + bn * 16 + lm);
      u64 key = ((u64)fkey(bv) << 32) | (u64)(0xFFFFFFFFu - colg);
#pragma unroll
      for (int off = 8; off >= 1; off >>= 1) {
        u64 o = __shfl_xor((unsigned long long)key, off, 64);
        if (o > key) key = o;
      }
      if (lm == 0) red[(wy * 64 + mi * 16 + q * 4 + r) * 2 + wx] = key;
    }
  }
  __syncthreads();
  if (t < 128) {
    u64 k0 = red[t * 2], k1 = red[t * 2 + 1];
    u64 b = k0 > k1 ? k0 : k1;
    partial[((size_t)(cb * 128 + t)) * 128 + sb] = b;
  }
}

// ---------- kernel 4: final 128-way reduce + gather ----------

__global__ __launch_bounds__(256) void argmax_gather_kernel(
    const u64* __restrict__ partial, const float* __restrict__ fs, float* __restrict__ out) {
  const int m = blockIdx.x, t = threadIdx.x;
  __shared__ u64 sred[2];
  u64 key = 0;
  if (t < 128) key = partial[(size_t)m * 128 + t];
#pragma unroll
  for (int off = 32; off >= 1; off >>= 1) {
    u64 o = __shfl_xor((unsigned long long)key, off, 64);
    if (o > key) key = o;
  }
  if (t < 128 && (t & 63) == 0) sred[t >> 6] = key;
  __syncthreads();
  u64 best = sred[0] > sred[1] ? sred[0] : sred[1];
  u32 col = 0xFFFFFFFFu - (u32)best;
  const float4* src = (const float4*)(fs + (size_t)col * DIM);
  float4* dst = (float4*)(out + (size_t)m * DIM);
  for (int i = t; i < D4; i += 256) dst[i] = src[i];
}

// ---------- launch ----------

extern "C" void kernel_launch(void* const* d_in, const int* in_sizes, int n_in,
                              void* d_out, int out_size, void* d_ws, size_t ws_size,
                              hipStream_t stream) {
  const float* fc = (const float*)d_in[0];
  const float* fs = (const float*)d_in[1];
  float* out = (float*)d_out;

  ushort_t* c_hi = (ushort_t*)d_ws;
  ushort_t* c_lo = c_hi + (size_t)NC_ * DIM;
  ushort_t* s_hi = c_lo + (size_t)NC_ * DIM;
  ushort_t* s_lo = s_hi + (size_t)NS_ * DIM;
  u64* partial = (u64*)(s_lo + (size_t)NS_ * DIM);  // 16384 * 128 u64

  content_split_kernel<<<(NC_ * DIM / 4 + 255) / 256, 256, 0, stream>>>(fc, c_hi, c_lo);
  style_split_kernel<<<NS_, 256, 0, stream>>>(fs, s_hi, s_lo);
  sim_argmax_kernel<<<16384, 256, 0, stream>>>(c_hi, c_lo, s_hi, s_lo, partial);
  argmax_gather_kernel<<<NC_, 256, 0, stream>>>(partial, fs, out);
}